// Round 1
// baseline (200.883 us; speedup 1.0000x reference)
//
#include <hip/hip_runtime.h>

// Problem dims
#define DD 32
#define NN 128
#define MH 5
#define NL_MID 4
#define BATCH 2048

// ws float offsets
#define WF_OFF 0                         // softplus10(w_first): [d][n][5]      = 20480
#define WM_OFF 20480                     // softplus10(w_mid):   [l][d][n][5][5]= 409600
#define WL_OFF 430080                    // softplus10(w_last):  [d][n][5]      = 20480
#define TA_OFF 450560                    // tanh(a_in):          [l][d][n][5]   = 102400
#define XT_OFF 552960                    // X transposed:        [d][b]         = 65536
#define S_OFF  618496                    // S[n][b]                             = 262144
#define TOTAL_PRE 618496                 // elements written by prep kernel

__device__ __forceinline__ float sp10(float x) {
    // softplus(10x)/10, stable form: max(y,0) + log1p(exp(-|y|))
    float y = 10.f * x;
    float r = fmaxf(y, 0.f) + log1pf(__expf(-fabsf(y)));
    return r * 0.1f;
}

__device__ __forceinline__ float fast_tanh(float x) {
    // tanh(x) = 1 - 2/(e^{2x}+1); saturates correctly at +-inf
    float e = __expf(2.f * x);
    return 1.f - 2.f / (e + 1.f);
}

// ---------------------------------------------------------------------------
// Kernel 1: transform weights (softplus10 / tanh) + transpose X, into ws.
// ---------------------------------------------------------------------------
__global__ __launch_bounds__(256) void prep_kernel(
    const float* __restrict__ X,
    const float* __restrict__ w_first,
    const float* __restrict__ w_mid,
    const float* __restrict__ w_last,
    const float* __restrict__ a_in,
    float* __restrict__ ws)
{
    int i = blockIdx.x * 256 + threadIdx.x;
    int stride = gridDim.x * 256;
    for (; i < TOTAL_PRE; i += stride) {
        float v;
        if (i < WM_OFF)       v = sp10(w_first[i]);
        else if (i < WL_OFF)  v = sp10(w_mid[i - WM_OFF]);
        else if (i < TA_OFF)  v = sp10(w_last[i - WL_OFF]);
        else if (i < XT_OFF)  v = tanhf(a_in[i - TA_OFF]);
        else {
            int j = i - XT_OFF;
            int d = j >> 11;          // j / 2048
            int b = j & 2047;
            v = X[b * DD + d];
        }
        ws[i] = v;
    }
}

// ---------------------------------------------------------------------------
// Kernel 2: per (b, n) evaluate the 6-layer MLP over all d, accumulate
//           S[b,n] = sum_d log(phidot + 1e-10).  Block = (n, b-chunk):
//           all weight addresses are wave-uniform -> scalar loads.
// ---------------------------------------------------------------------------
__global__ __launch_bounds__(256) void mlp_kernel(
    const float* __restrict__ ws,
    const float* __restrict__ b_in,
    const float* __restrict__ b_last,
    float* __restrict__ Sout)
{
    const int n = blockIdx.x;                       // 0..127
    const int b = blockIdx.y * 256 + threadIdx.x;   // 0..2047
    const float* __restrict__ XT = ws + XT_OFF;

    float slog = 0.f;
    for (int d = 0; d < DD; ++d) {
        const int dn = d * NN + n;
        const float x = XT[d * BATCH + b];

        const float* wf  = ws + WF_OFF + dn * MH;
        const float* ta0 = ws + TA_OFF + dn * MH;       // layer 0
        const float* bi0 = b_in + dn * MH;              // layer 0

        float phis[MH], phid[MH];
#pragma unroll
        for (int m = 0; m < MH; ++m) {
            float W   = wf[m];
            float pre = fmaf(x, W, bi0[m]);
            float ta  = ta0[m];
            float tp  = fast_tanh(pre);
            phis[m] = fmaf(tp, ta, pre);
            phid[m] = W * fmaf(ta, 1.f - tp * tp, 1.f); // gate, phidots_in = 1
        }

#pragma unroll
        for (int l = 0; l < NL_MID; ++l) {
            const float* wm = ws + WM_OFF + (l * DD * NN + dn) * (MH * MH);
            const float* bi = b_in + ((l + 1) * DD * NN + dn) * MH;
            const float* ta = ws + TA_OFF + ((l + 1) * DD * NN + dn) * MH;
            float np_[MH], nd_[MH];
#pragma unroll
            for (int m = 0; m < MH; ++m) {
                float pre = bi[m];
                float pd  = 0.f;
#pragma unroll
                for (int k = 0; k < MH; ++k) {
                    float W = wm[k * MH + m];
                    pre = fmaf(phis[k], W, pre);
                    pd  = fmaf(phid[k], W, pd);
                }
                float tam = ta[m];
                float tp  = fast_tanh(pre);
                np_[m] = fmaf(tp, tam, pre);
                nd_[m] = pd * fmaf(tam, 1.f - tp * tp, 1.f);
            }
#pragma unroll
            for (int m = 0; m < MH; ++m) { phis[m] = np_[m]; phid[m] = nd_[m]; }
        }

        // last layer: 5 -> 1, sigmoid-derivative gate
        const float* wl = ws + WL_OFF + dn * MH;
        float pre = b_last[dn];
        float pd  = 0.f;
#pragma unroll
        for (int k = 0; k < MH; ++k) {
            float W = wl[k];
            pre = fmaf(phis[k], W, pre);
            pd  = fmaf(phid[k], W, pd);
        }
        float sg = 1.f / (1.f + __expf(-pre));
        float phidot = pd * sg * (1.f - sg);
        slog += __logf(phidot + 1e-10f);
    }
    Sout[n * BATCH + b] = slog;   // [n][b] layout: coalesced store
}

// ---------------------------------------------------------------------------
// Kernel 3: per b, weighted log-sum-exp over n.
//   out[b] = log( sum_n anorm[n]*exp(S[b,n]-Smax) + 1e-10 ) + Smax
// ---------------------------------------------------------------------------
__global__ __launch_bounds__(128) void finalize_kernel(
    const float* __restrict__ S,
    const float* __restrict__ a_last,
    float* __restrict__ out)
{
    const int b = blockIdx.x;
    const int n = threadIdx.x;
    __shared__ float sh[NN];
    __shared__ float sh2[NN];

    float s = S[n * BATCH + b];
    sh[n] = s;
    __syncthreads();
    for (int off = NN / 2; off > 0; off >>= 1) {
        if (n < off) sh[n] = fmaxf(sh[n], sh[n + off]);
        __syncthreads();
    }
    float smax = sh[0];
    __syncthreads();

    float an = sp10(a_last[n]);
    float p  = __expf(s - smax) * an;
    sh[n]  = p;
    sh2[n] = an;
    __syncthreads();
    for (int off = NN / 2; off > 0; off >>= 1) {
        if (n < off) { sh[n] += sh[n + off]; sh2[n] += sh2[n + off]; }
        __syncthreads();
    }
    if (n == 0) out[b] = __logf(sh[0] / sh2[0] + 1e-10f) + smax;
}

extern "C" void kernel_launch(void* const* d_in, const int* in_sizes, int n_in,
                              void* d_out, int out_size, void* d_ws, size_t ws_size,
                              hipStream_t stream)
{
    const float* X       = (const float*)d_in[0];
    const float* w_first = (const float*)d_in[1];
    const float* w_mid   = (const float*)d_in[2];
    const float* w_last  = (const float*)d_in[3];
    const float* b_in    = (const float*)d_in[4];
    const float* b_last  = (const float*)d_in[5];
    const float* a_in    = (const float*)d_in[6];
    const float* a_last  = (const float*)d_in[7];
    float* out = (float*)d_out;
    float* ws  = (float*)d_ws;

    prep_kernel<<<1024, 256, 0, stream>>>(X, w_first, w_mid, w_last, a_in, ws);

    dim3 g2(NN, BATCH / 256);
    mlp_kernel<<<g2, 256, 0, stream>>>(ws, b_in, b_last, ws + S_OFF);

    finalize_kernel<<<BATCH, NN, 0, stream>>>(ws + S_OFF, a_last, out);
}

// Round 2
// 103.172 us; speedup vs baseline: 1.9471x; 1.9471x over previous
//
#include <hip/hip_runtime.h>

// Problem dims
#define DD 32
#define NN 128
#define MH 5
#define NL_MID 4
#define BATCH 2048

// ws float offsets
#define WF_OFF 0                         // softplus10(w_first): [d][n][5]      = 20480
#define WM_OFF 20480                     // softplus10(w_mid):   [l][d][n][5][5]= 409600
#define WL_OFF 430080                    // softplus10(w_last):  [d][n][5]      = 20480
#define TA_OFF 450560                    // tanh(a_in):          [l][d][n][5]   = 102400
#define XT_OFF 552960                    // X transposed:        [d][b]         = 65536
#define SP_OFF 618496                    // partial S: [2][n][b]                = 524288
#define TOTAL_PRE 618496                 // elements written by prep kernel

typedef float v2 __attribute__((ext_vector_type(2)));

__device__ __forceinline__ v2 v2fma(v2 a, v2 b, v2 c) { return __builtin_elementwise_fma(a, b, c); }
__device__ __forceinline__ float rcpf(float x)  { return __builtin_amdgcn_rcpf(x); }
__device__ __forceinline__ float exp2f_(float x){ return __builtin_amdgcn_exp2f(x); }
__device__ __forceinline__ float log2f_(float x){ return __builtin_amdgcn_logf(x); }

#define LOG2E 1.442695041f

__device__ __forceinline__ float sp10(float x) {
    // softplus(10x)/10, stable form
    float y = 10.f * x;
    float r = fmaxf(y, 0.f) + log1pf(__expf(-fabsf(y)));
    return r * 0.1f;
}

// tanh of both components + (1 - tanh^2), one exp + one rcp per component
__device__ __forceinline__ void tanh2(v2 pre, v2& tp, v2& omt2) {
    const float K = 2.f * LOG2E;        // exp(2x) = exp2(K x)
    float e0 = exp2f_(pre.x * K);
    float e1 = exp2f_(pre.y * K);
    float r0 = rcpf(e0 + 1.f);
    float r1 = rcpf(e1 + 1.f);
    v2 r = { r0, r1 };
    tp   = v2fma(r, (v2)(-2.f), (v2)(1.f));   // 1 - 2r
    omt2 = v2fma(-tp, tp, (v2)(1.f));         // 1 - tp^2
}

// ---------------------------------------------------------------------------
// Kernel 1: transform weights (softplus10 / tanh) + transpose X, into ws.
// ---------------------------------------------------------------------------
__global__ __launch_bounds__(256) void prep_kernel(
    const float* __restrict__ X,
    const float* __restrict__ w_first,
    const float* __restrict__ w_mid,
    const float* __restrict__ w_last,
    const float* __restrict__ a_in,
    float* __restrict__ ws)
{
    int i = blockIdx.x * 256 + threadIdx.x;
    int stride = gridDim.x * 256;
    for (; i < TOTAL_PRE; i += stride) {
        float v;
        if (i < WM_OFF)       v = sp10(w_first[i]);
        else if (i < WL_OFF)  v = sp10(w_mid[i - WM_OFF]);
        else if (i < TA_OFF)  v = sp10(w_last[i - WL_OFF]);
        else if (i < XT_OFF)  v = tanhf(a_in[i - TA_OFF]);
        else {
            int j = i - XT_OFF;
            int d = j >> 11;          // j / 2048
            int b = j & 2047;
            v = X[b * DD + d];
        }
        ws[i] = v;
    }
}

// ---------------------------------------------------------------------------
// Kernel 2: per (b-pair, n, d-half) evaluate the 6-layer MLP, accumulate
//           partial S in log2 units. Two batch elements per thread as v2
//           (targets v_pk_*_f32). Weight addresses wave-uniform -> scalar.
// ---------------------------------------------------------------------------
__global__ __launch_bounds__(256) void mlp_kernel(
    const float* __restrict__ ws,
    const float* __restrict__ b_in,
    const float* __restrict__ b_last,
    float* __restrict__ Sp)
{
    const int n  = blockIdx.x;                        // 0..127
    const int h  = blockIdx.y;                        // 0..1 (d half)
    const int bp = blockIdx.z * 256 + threadIdx.x;    // 0..1023 (batch pair)
    const float* __restrict__ XT = ws + XT_OFF;

    v2 slog2 = { 0.f, 0.f };
    const int d0 = h * (DD / 2), d1 = d0 + (DD / 2);

    for (int d = d0; d < d1; ++d) {
        const int dn = d * NN + n;
        const v2 x = *(const v2*)(XT + d * BATCH + 2 * bp);

        const float* wf  = ws + WF_OFF + dn * MH;
        const float* ta0 = ws + TA_OFF + dn * MH;
        const float* bi0 = b_in + dn * MH;

        v2 phis[MH], phid[MH];
#pragma unroll
        for (int m = 0; m < MH; ++m) {
            float W  = wf[m];
            float ta = ta0[m];
            v2 pre = v2fma(x, (v2)W, (v2)bi0[m]);
            v2 tp, omt2;
            tanh2(pre, tp, omt2);
            phis[m] = v2fma(tp, (v2)ta, pre);
            v2 gate = v2fma((v2)ta, omt2, (v2)(1.f));
            phid[m] = (v2)W * gate;                  // phidots_in = 1
        }

#pragma unroll
        for (int l = 0; l < NL_MID; ++l) {
            const float* wm = ws + WM_OFF + (l * DD * NN + dn) * (MH * MH);
            const float* bi = b_in + ((l + 1) * DD * NN + dn) * MH;
            const float* ta = ws + TA_OFF + ((l + 1) * DD * NN + dn) * MH;
            v2 np_[MH], nd_[MH];
#pragma unroll
            for (int m = 0; m < MH; ++m) {
                v2 pre = (v2)bi[m];
                v2 pd  = { 0.f, 0.f };
#pragma unroll
                for (int k = 0; k < MH; ++k) {
                    float W = wm[k * MH + m];
                    pre = v2fma(phis[k], (v2)W, pre);
                    pd  = v2fma(phid[k], (v2)W, pd);
                }
                float tam = ta[m];
                v2 tp, omt2;
                tanh2(pre, tp, omt2);
                np_[m] = v2fma(tp, (v2)tam, pre);
                v2 gate = v2fma((v2)tam, omt2, (v2)(1.f));
                nd_[m] = pd * gate;
            }
#pragma unroll
            for (int m = 0; m < MH; ++m) { phis[m] = np_[m]; phid[m] = nd_[m]; }
        }

        // last layer: 5 -> 1, sigmoid-derivative gate
        const float* wl = ws + WL_OFF + dn * MH;
        v2 pre = (v2)b_last[dn];
        v2 pd  = { 0.f, 0.f };
#pragma unroll
        for (int k = 0; k < MH; ++k) {
            float W = wl[k];
            pre = v2fma(phis[k], (v2)W, pre);
            pd  = v2fma(phid[k], (v2)W, pd);
        }
        // sigmoid'(pre) = e*r^2 with e = exp(-pre), r = 1/(1+e)
        float e0 = exp2f_(pre.x * -LOG2E);
        float e1 = exp2f_(pre.y * -LOG2E);
        float r0 = rcpf(1.f + e0);
        float r1 = rcpf(1.f + e1);
        v2 sd = { e0 * r0 * r0, e1 * r1 * r1 };
        v2 phidot = pd * sd;
        v2 lg = { log2f_(phidot.x + 1e-10f), log2f_(phidot.y + 1e-10f) };
        slog2 += lg;
    }

    v2 out = slog2 * (v2)(0.6931471806f);            // back to natural log
    *(v2*)(Sp + (h * NN + n) * BATCH + 2 * bp) = out;
}

// ---------------------------------------------------------------------------
// Kernel 3: per b, weighted log-sum-exp over n (summing the two d-halves).
// ---------------------------------------------------------------------------
__global__ __launch_bounds__(128) void finalize_kernel(
    const float* __restrict__ Sp,
    const float* __restrict__ a_last,
    float* __restrict__ out)
{
    const int b = blockIdx.x;
    const int n = threadIdx.x;
    __shared__ float sh[NN];
    __shared__ float sh2[NN];

    float s = Sp[n * BATCH + b] + Sp[(NN + n) * BATCH + b];
    sh[n] = s;
    __syncthreads();
    for (int off = NN / 2; off > 0; off >>= 1) {
        if (n < off) sh[n] = fmaxf(sh[n], sh[n + off]);
        __syncthreads();
    }
    float smax = sh[0];
    __syncthreads();

    float an = sp10(a_last[n]);
    float p  = __expf(s - smax) * an;
    sh[n]  = p;
    sh2[n] = an;
    __syncthreads();
    for (int off = NN / 2; off > 0; off >>= 1) {
        if (n < off) { sh[n] += sh[n + off]; sh2[n] += sh2[n + off]; }
        __syncthreads();
    }
    if (n == 0) out[b] = __logf(sh[0] / sh2[0] + 1e-10f) + smax;
}

extern "C" void kernel_launch(void* const* d_in, const int* in_sizes, int n_in,
                              void* d_out, int out_size, void* d_ws, size_t ws_size,
                              hipStream_t stream)
{
    const float* X       = (const float*)d_in[0];
    const float* w_first = (const float*)d_in[1];
    const float* w_mid   = (const float*)d_in[2];
    const float* w_last  = (const float*)d_in[3];
    const float* b_in    = (const float*)d_in[4];
    const float* b_last  = (const float*)d_in[5];
    const float* a_in    = (const float*)d_in[6];
    const float* a_last  = (const float*)d_in[7];
    float* out = (float*)d_out;
    float* ws  = (float*)d_ws;

    prep_kernel<<<1024, 256, 0, stream>>>(X, w_first, w_mid, w_last, a_in, ws);

    dim3 g2(NN, 2, BATCH / 2 / 256);
    mlp_kernel<<<g2, 256, 0, stream>>>(ws, b_in, b_last, ws + SP_OFF);

    finalize_kernel<<<BATCH, NN, 0, stream>>>(ws + SP_OFF, a_last, out);
}